// Round 1
// baseline (740.397 us; speedup 1.0000x reference)
//
#include <hip/hip_runtime.h>
#include <hip/hip_bf16.h>

typedef __hip_bfloat16 bf16;

// Problem constants (B=8, C=256, H=W=64, sd=128, HEADS=8, hd=16, L=256)
// Window combos per shift: idx0 = 64x4 column strips (16 per image),
//                          idx1 = 4x64 row strips   (16 per image).
// Channel layout inside a part: c = d*8 + head  (hd outer, head inner).
// Window tensors stored channel-major: [winG(128)][hc=head*16+d (128)][t(256)]
// per combo, bf16. v also stored spatially [b][c][h][w] bf16 for LePE.

#define WIN_ELEMS 4194304  // 128 win * 128 ch * 256 t  (also 8*128*64*64)

// ---------------- wq transpose:  wqT[c][o] = w_qkv[o][c] ----------------
__global__ void k_transpose_wq(const float* __restrict__ wq,
                               float* __restrict__ wqT) {
    int i = blockIdx.x * blockDim.x + threadIdx.x;
    if (i >= 384 * 128) return;
    int o = i % 384;
    int c = i / 384;
    wqT[c * 384 + o] = wq[o * 128 + c];
}

// ---------------- projection + window scatter ----------------
// grid (4 quarters, 128 windows, 2 idx), block 256
__global__ __launch_bounds__(256) void k_proj(
    const float* __restrict__ x, const float* __restrict__ wqT,
    bf16* __restrict__ ws_bf, int s)
{
    const int qq   = blockIdx.x;        // quarter of window (64 tokens)
    const int winG = blockIdx.y;        // b*16 + wi
    const int idx  = blockIdx.z;        // strip direction
    const int b = winG >> 4, wi = winG & 15;
    const int tid = threadIdx.x;

    __shared__ float xt[64 * 129];      // [pixel][c], pad 129 (conflict-free)

    // stage x (rolled channels gc=(idx*128+c+s)&255, rolled rows gh=(h+s)&63)
    for (int i = tid; i < 64 * 128; i += 256) {
        int c = i >> 6, p = i & 63;
        int t = qq * 64 + p;
        int h, w;
        if (idx == 0) { h = t >> 2;            w = wi * 4 + (t & 3); }
        else          { h = wi * 4 + (t >> 6); w = t & 63; }
        int gc = (idx * 128 + c + s) & 255;
        int gh = (h + s) & 63;
        xt[p * 129 + c] = x[((b * 256 + gc) << 12) + (gh << 6) + w];
    }
    __syncthreads();

    const int lane = tid & 63;
    const int p = lane;
    const int obase = __builtin_amdgcn_readfirstlane((tid >> 6) * 96);

    const int t = qq * 64 + p;
    int h, w;
    if (idx == 0) { h = t >> 2;            w = wi * 4 + (t & 3); }
    else          { h = wi * 4 + (t >> 6); w = t & 63; }

    bf16* qw  = ws_bf + (size_t)(idx * 4 + 0) * WIN_ELEMS;
    bf16* kw  = ws_bf + (size_t)(idx * 4 + 1) * WIN_ELEMS;
    bf16* vw  = ws_bf + (size_t)(idx * 4 + 2) * WIN_ELEMS;
    bf16* vsp = ws_bf + (size_t)(idx * 4 + 3) * WIN_ELEMS;

    for (int og = 0; og < 6; ++og) {
        const int o0 = obase + og * 16;     // 16-aligned, stays inside one part
        float acc[16];
        #pragma unroll
        for (int j = 0; j < 16; ++j) acc[j] = 0.f;

        const float* __restrict__ wp = wqT + o0;
        for (int c = 0; c < 128; ++c) {
            float xv = xt[p * 129 + c];
            const float* wr = wp + c * 384;     // wave-uniform -> s_load
            #pragma unroll
            for (int j = 0; j < 16; ++j) acc[j] = fmaf(xv, wr[j], acc[j]);
        }

        const int part = o0 >> 7;   // 0=q, 1=k, 2=v (uniform within group)
        #pragma unroll
        for (int j = 0; j < 16; ++j) {
            int o = o0 + j;
            int c = o & 127;
            float val = acc[j];
            if (part == 0) val *= 0.25f;        // fold softmax scale into q
            int hc = (c & 7) * 16 + (c >> 3);   // head*16 + d
            bf16 bv = __float2bfloat16(val);
            size_t waddr = ((size_t)(winG * 128 + hc) << 8) + t;
            if (part == 0)      qw[waddr] = bv;
            else if (part == 1) kw[waddr] = bv;
            else {
                vw[waddr] = bv;
                vsp[((size_t)(b * 128 + c) << 12) + (h << 6) + w] = bv;
            }
        }
    }
}

// ---------------- flash attention (2-pass) + LePE + roll-back ----------------
// grid (8 heads, 128 windows, 2 idx), block 256 (thread = query row)
template<bool ACCUM>
__global__ __launch_bounds__(256) void k_attn(
    const bf16* __restrict__ ws_bf,
    const float* __restrict__ w_lepe, const float* __restrict__ b_lepe,
    float* __restrict__ out, int s)
{
    const int head = blockIdx.x, winG = blockIdx.y, idx = blockIdx.z;
    const int b = winG >> 4, wi = winG & 15;
    const int t = threadIdx.x;

    __shared__ float kt[256 * 20];   // pad 20 -> 16B-aligned rows for b128
    __shared__ float vt[256 * 20];

    const bf16* qw  = ws_bf + (size_t)(idx * 4 + 0) * WIN_ELEMS;
    const bf16* kw  = ws_bf + (size_t)(idx * 4 + 1) * WIN_ELEMS;
    const bf16* vw  = ws_bf + (size_t)(idx * 4 + 2) * WIN_ELEMS;
    const bf16* vsp = ws_bf + (size_t)(idx * 4 + 3) * WIN_ELEMS;

    float qr[16];
    #pragma unroll
    for (int d = 0; d < 16; ++d) {
        size_t base = (size_t)(winG * 128 + head * 16 + d) << 8;
        kt[t * 20 + d] = __bfloat162float(kw[base + t]);
        vt[t * 20 + d] = __bfloat162float(vw[base + t]);
        qr[d]          = __bfloat162float(qw[base + t]);   // already *0.25
    }
    __syncthreads();

    // pass 1: row max
    float m = -1e30f;
    for (int j = 0; j < 256; ++j) {
        const float* krow = kt + j * 20;   // uniform addr -> LDS broadcast
        float sd = 0.f;
        #pragma unroll
        for (int d = 0; d < 16; ++d) sd = fmaf(qr[d], krow[d], sd);
        m = fmaxf(m, sd);
    }
    // pass 2: exp-sum + PV accumulate
    float l = 0.f;
    float acc[16];
    #pragma unroll
    for (int d = 0; d < 16; ++d) acc[d] = 0.f;
    for (int j = 0; j < 256; ++j) {
        const float* krow = kt + j * 20;
        float sd = 0.f;
        #pragma unroll
        for (int d = 0; d < 16; ++d) sd = fmaf(qr[d], krow[d], sd);
        float pv = __expf(sd - m);
        l += pv;
        const float* vrow = vt + j * 20;
        #pragma unroll
        for (int d = 0; d < 16; ++d) acc[d] = fmaf(pv, vrow[d], acc[d]);
    }
    const float inv = 1.f / l;

    int h, w;
    if (idx == 0) { h = t >> 2;            w = wi * 4 + (t & 3); }
    else          { h = wi * 4 + (t >> 6); w = t & 63; }

    for (int d = 0; d < 16; ++d) {
        int c = d * 8 + head;
        float lep = b_lepe[c];
        #pragma unroll
        for (int ky = 0; ky < 3; ++ky) {
            int hh = h + ky - 1;
            if (hh < 0 || hh > 63) continue;
            #pragma unroll
            for (int kx = 0; kx < 3; ++kx) {
                int ww = w + kx - 1;
                if (ww < 0 || ww > 63) continue;
                lep = fmaf(w_lepe[c * 9 + ky * 3 + kx],
                           __bfloat162float(
                               vsp[((size_t)(b * 128 + c) << 12) + (hh << 6) + ww]),
                           lep);
            }
        }
        float o = fmaf(acc[d], inv, lep);
        // inverse roll: channel (c+s)%128 inside part, row (h+s)%64
        int oc = idx * 128 + ((c + s) & 127);
        int oh = (h + s) & 63;
        size_t oaddr = ((size_t)(b * 256 + oc) << 12) + (oh << 6) + w;
        if (ACCUM) out[oaddr] += o;
        else       out[oaddr] = o;
    }
}

extern "C" void kernel_launch(void* const* d_in, const int* in_sizes, int n_in,
                              void* d_out, int out_size, void* d_ws, size_t ws_size,
                              hipStream_t stream) {
    const float* x      = (const float*)d_in[0];
    const float* w_qkv  = (const float*)d_in[1];
    const float* w_lepe = (const float*)d_in[2];
    const float* b_lepe = (const float*)d_in[3];
    float* out = (float*)d_out;

    float* wqT   = (float*)d_ws;                          // 384*128 fp32
    bf16*  ws_bf = (bf16*)((char*)d_ws + 196608);         // 8 window tensors

    k_transpose_wq<<<192, 256, 0, stream>>>(w_qkv, wqT);

    // shift 0: writes out directly (full coverage), shift 2: accumulates
    k_proj<<<dim3(4, 128, 2), 256, 0, stream>>>(x, wqT, ws_bf, 0);
    k_attn<false><<<dim3(8, 128, 2), 256, 0, stream>>>(ws_bf, w_lepe, b_lepe, out, 0);
    k_proj<<<dim3(4, 128, 2), 256, 0, stream>>>(x, wqT, ws_bf, 2);
    k_attn<true><<<dim3(8, 128, 2), 256, 0, stream>>>(ws_bf, w_lepe, b_lepe, out, 2);
}

// Round 2
// 555.820 us; speedup vs baseline: 1.3321x; 1.3321x over previous
//
#include <hip/hip_runtime.h>
#include <hip/hip_bf16.h>

typedef _Float16 f16;
typedef _Float16 half4 __attribute__((ext_vector_type(4)));
typedef float floatx4 __attribute__((ext_vector_type(4)));

// Problem constants (B=8, C=256, H=W=64, sd=128, HEADS=8, hd=16, L=256)
// Window combos per idx: idx0 = 64x4 column strips, idx1 = 4x64 row strips.
// Part channel c = d*8 + head.
// Window tensors (f16), per idx:
//   qw,kw: token-major   [winG(128)][head(8)][t(256)][d(16)]
//   vw:    channel-major [winG(128)][head(8)][d(16)][t(256)]
//   vsp:   spatial       [b(8)][c(128)][h(64)][w(64)]   (for LePE)

#define WIN_ELEMS 4194304  // 128*8*256*16 elems = 8*128*64*64

// ---------------- wq transpose:  wqT[c][o] = w_qkv[o][c] ----------------
__global__ void k_transpose_wq(const float* __restrict__ wq,
                               float* __restrict__ wqT) {
    int i = blockIdx.x * blockDim.x + threadIdx.x;
    if (i >= 384 * 128) return;
    int o = i % 384;
    int c = i / 384;
    wqT[c * 384 + o] = wq[o * 128 + c];
}

// ---------------- projection + window scatter ----------------
// grid (4 quarters, 128 windows, 2 idx), block 256
__global__ __launch_bounds__(256) void k_proj(
    const float* __restrict__ x, const float* __restrict__ wqT,
    f16* __restrict__ ws, int s)
{
    const int qq   = blockIdx.x;        // quarter of window (64 tokens)
    const int winG = blockIdx.y;        // b*16 + wi
    const int idx  = blockIdx.z;        // strip direction
    const int b = winG >> 4, wi = winG & 15;
    const int tid = threadIdx.x;

    __shared__ float xt[64 * 129];      // [pixel][c], pad 129

    // stage x (rolled channels gc=(idx*128+c+s)&255, rolled rows gh=(h+s)&63)
    for (int i = tid; i < 64 * 128; i += 256) {
        int c = i >> 6, p = i & 63;
        int t = qq * 64 + p;
        int h, w;
        if (idx == 0) { h = t >> 2;            w = wi * 4 + (t & 3); }
        else          { h = wi * 4 + (t >> 6); w = t & 63; }
        int gc = (idx * 128 + c + s) & 255;
        int gh = (h + s) & 63;
        xt[p * 129 + c] = x[((b * 256 + gc) << 12) + (gh << 6) + w];
    }
    __syncthreads();

    const int p = tid & 63;
    const int obase = __builtin_amdgcn_readfirstlane((tid >> 6) * 96);

    const int t = qq * 64 + p;
    int h, w;
    if (idx == 0) { h = t >> 2;            w = wi * 4 + (t & 3); }
    else          { h = wi * 4 + (t >> 6); w = t & 63; }

    f16* qw  = ws + (size_t)(idx * 4 + 0) * WIN_ELEMS;
    f16* kw  = ws + (size_t)(idx * 4 + 1) * WIN_ELEMS;
    f16* vw  = ws + (size_t)(idx * 4 + 2) * WIN_ELEMS;
    f16* vsp = ws + (size_t)(idx * 4 + 3) * WIN_ELEMS;

    for (int og = 0; og < 6; ++og) {
        const int o0 = obase + og * 16;     // 16-aligned, inside one part
        float acc[16];
        #pragma unroll
        for (int j = 0; j < 16; ++j) acc[j] = 0.f;

        const float* __restrict__ wp = wqT + o0;
        for (int c = 0; c < 128; ++c) {
            float xv = xt[p * 129 + c];
            const float* wr = wp + c * 384;     // wave-uniform -> s_load
            #pragma unroll
            for (int j = 0; j < 16; ++j) acc[j] = fmaf(xv, wr[j], acc[j]);
        }

        const int part = o0 >> 7;   // 0=q, 1=k, 2=v
        #pragma unroll
        for (int j = 0; j < 16; ++j) {
            int o = o0 + j;
            int c = o & 127;
            int head = c & 7, d = c >> 3;
            float val = acc[j];
            if (part == 0) val *= 0.25f;        // fold softmax scale into q
            f16 hv = (f16)val;
            if (part == 0) {
                qw[((size_t)(winG * 8 + head) * 256 + t) * 16 + d] = hv;
            } else if (part == 1) {
                kw[((size_t)(winG * 8 + head) * 256 + t) * 16 + d] = hv;
            } else {
                vw[((size_t)(winG * 8 + head) * 16 + d) * 256 + t] = hv;
                vsp[((size_t)(b * 128 + c) << 12) + (h << 6) + w] = hv;
            }
        }
    }
}

// ---------------- MFMA attention + LePE + roll-back ----------------
// One wave = (winG, idx, head, query-half of 128 rows).
// grid 1024 blocks x 256 threads per shift -> 4096 waves.
// S^T = K.Q^T via mfma 16x16x16 f16; C-frag of S^T == B-frag of P^T
// for the PV mfma O^T = V^T.P^T  (transpose-free handoff).
template<bool ACCUM>
__global__ __launch_bounds__(256) void k_attn(
    const f16* __restrict__ ws,
    const float* __restrict__ w_lepe, const float* __restrict__ b_lepe,
    float* __restrict__ out, int s)
{
    const int lane  = threadIdx.x & 63;
    const int g     = lane >> 4;      // lane quad-group 0..3
    const int ln    = lane & 15;
    const int W     = blockIdx.x * 4 + (threadIdx.x >> 6);
    const int qhalf = W & 1;
    const int head  = (W >> 1) & 7;
    const int idx   = (W >> 4) & 1;
    const int winG  = W >> 5;
    const int b = winG >> 4, wi = winG & 15;

    const f16* qw  = ws + (size_t)(idx * 4 + 0) * WIN_ELEMS;
    const f16* kw  = ws + (size_t)(idx * 4 + 1) * WIN_ELEMS;
    const f16* vw  = ws + (size_t)(idx * 4 + 2) * WIN_ELEMS;
    const f16* vsp = ws + (size_t)(idx * 4 + 3) * WIN_ELEMS;

    const size_t tkbase = (size_t)(winG * 8 + head) * 256;  // token-major base
    const size_t vbase  = (size_t)(winG * 8 + head) * 16;   // channel-major base

    // Q^T B-frags: B[k=d=g*4+j][n=query=ln]
    half4 qf[8];
    #pragma unroll
    for (int qt = 0; qt < 8; ++qt) {
        int t = qhalf * 128 + qt * 16 + ln;
        qf[qt] = *(const half4*)(qw + (tkbase + t) * 16 + g * 4);
    }

    floatx4 o[8];
    float lsum[8];
    #pragma unroll
    for (int qt = 0; qt < 8; ++qt) {
        o[qt] = (floatx4){0.f, 0.f, 0.f, 0.f};
        lsum[qt] = 0.f;
    }

    for (int kt = 0; kt < 16; ++kt) {
        // K A-frag: A[m=key=ln][k=d=g*4+j]
        half4 kf = *(const half4*)(kw + (tkbase + kt * 16 + ln) * 16 + g * 4);
        // V^T A-frag: A[m=d=ln][k=key=g*4+j]
        half4 vf = *(const half4*)(vw + (vbase + ln) * 256 + kt * 16 + g * 4);
        #pragma unroll
        for (int qt = 0; qt < 8; ++qt) {
            // S^T tile: c[reg] = S[key=kt*16+g*4+reg][query=qt*16+ln]
            floatx4 c = __builtin_amdgcn_mfma_f32_16x16x16f16(
                kf, qf[qt], (floatx4){0.f, 0.f, 0.f, 0.f}, 0, 0, 0);
            // max-free softmax: |S| is tiny (q pre-scaled by 0.25)
            float p0 = __expf(c[0]);
            float p1 = __expf(c[1]);
            float p2 = __expf(c[2]);
            float p3 = __expf(c[3]);
            lsum[qt] += (p0 + p1) + (p2 + p3);
            half4 pf = {(f16)p0, (f16)p1, (f16)p2, (f16)p3};
            // O^T += V^T . P^T : C[row=d][col=query]
            o[qt] = __builtin_amdgcn_mfma_f32_16x16x16f16(vf, pf, o[qt], 0, 0, 0);
        }
    }

    // LePE weights for this lane's 4 channels (qt-invariant)
    float wl[4][9], bl[4];
    #pragma unroll
    for (int r = 0; r < 4; ++r) {
        int c = (g * 4 + r) * 8 + head;
        bl[r] = b_lepe[c];
        #pragma unroll
        for (int tp = 0; tp < 9; ++tp) wl[r][tp] = w_lepe[c * 9 + tp];
    }

    for (int qt = 0; qt < 8; ++qt) {
        float l = lsum[qt];
        l += __shfl_xor(l, 16);
        l += __shfl_xor(l, 32);
        const float inv = 1.f / l;

        int t = qhalf * 128 + qt * 16 + ln;
        int h, w;
        if (idx == 0) { h = t >> 2;            w = wi * 4 + (t & 3); }
        else          { h = wi * 4 + (t >> 6); w = t & 63; }

        #pragma unroll
        for (int r = 0; r < 4; ++r) {
            int d = g * 4 + r;
            int c = d * 8 + head;
            float lep = bl[r];
            #pragma unroll
            for (int ky = 0; ky < 3; ++ky) {
                int hh = h + ky - 1;
                if (hh < 0 || hh > 63) continue;
                #pragma unroll
                for (int kx = 0; kx < 3; ++kx) {
                    int ww = w + kx - 1;
                    if (ww < 0 || ww > 63) continue;
                    lep = fmaf(wl[r][ky * 3 + kx],
                               (float)vsp[((size_t)(b * 128 + c) << 12) + (hh << 6) + ww],
                               lep);
                }
            }
            float val = fmaf(o[qt][r], inv, lep);
            int oc = idx * 128 + ((c + s) & 127);
            int oh = (h + s) & 63;
            size_t oaddr = ((size_t)(b * 256 + oc) << 12) + (oh << 6) + w;
            if (ACCUM) out[oaddr] += val;
            else       out[oaddr] = val;
        }
    }
}

extern "C" void kernel_launch(void* const* d_in, const int* in_sizes, int n_in,
                              void* d_out, int out_size, void* d_ws, size_t ws_size,
                              hipStream_t stream) {
    const float* x      = (const float*)d_in[0];
    const float* w_qkv  = (const float*)d_in[1];
    const float* w_lepe = (const float*)d_in[2];
    const float* b_lepe = (const float*)d_in[3];
    float* out = (float*)d_out;

    float* wqT = (float*)d_ws;                       // 384*128 fp32
    f16*   ws  = (f16*)((char*)d_ws + 196608);       // 8 window tensors

    k_transpose_wq<<<192, 256, 0, stream>>>(w_qkv, wqT);

    // shift 0 writes out (full coverage), shift 2 accumulates
    k_proj<<<dim3(4, 128, 2), 256, 0, stream>>>(x, wqT, ws, 0);
    k_attn<false><<<1024, 256, 0, stream>>>(ws, w_lepe, b_lepe, out, 0);
    k_proj<<<dim3(4, 128, 2), 256, 0, stream>>>(x, wqT, ws, 2);
    k_attn<true><<<1024, 256, 0, stream>>>(ws, w_lepe, b_lepe, out, 2);
}

// Round 3
// 355.221 us; speedup vs baseline: 2.0843x; 1.5647x over previous
//
#include <hip/hip_runtime.h>
#include <hip/hip_bf16.h>

typedef _Float16 f16;
typedef _Float16 half4 __attribute__((ext_vector_type(4)));
typedef float floatx4 __attribute__((ext_vector_type(4)));

// Problem: B=8, C=256, H=W=64, sd=128, HEADS=8, hd=16, window L=256 tokens.
// idx0 = 64x4 column strips (wi = w>>2), idx1 = 4x64 row strips (wi = h>>2).
// Unified c-major window layout for q/k/v/lepe/ow (f16):
//   [winG(128)][head(8)][d(16)][t(256)]  -> addr ((winG*8+head)*16+d)*256 + t
// WIN = elems per [idx] tensor.
#define WIN 4194304

// ws layout (f16 elems): wqB pad 65536 | qw 2W | kw 2W | vw 2W | lepe 2W | ow0 2W
// = 84 MB. Shift-2 attention output aliases qw (race-free: each wave writes
// only the q region it already loaded).

// ---- weight prep: wqB[part][kt][nt][lane][kj] (B-frag-ordered, dwordx2/lane)
__global__ void k_prep(const float* __restrict__ wq, f16* __restrict__ wqB) {
    int D = blockIdx.x * 256 + threadIdx.x;
    if (D >= 49152) return;
    int kj = D & 3, lane = (D >> 2) & 63, nt = (D >> 8) & 7;
    int kt = (D >> 11) & 7, part = D >> 14;
    int g = lane >> 4, ln = lane & 15;
    int o = part * 128 + nt * 16 + ln;
    int k = kt * 16 + g * 4 + kj;
    wqB[D] = (f16)wq[o * 128 + k];
}

// ---- MFMA projection: per window GEMM [256 t x 128 c] x [128 c x 384 o]
// grid (128 winG, 2 idx), 256 threads (4 waves x 64-token M-slices)
__global__ __launch_bounds__(256, 1) void k_proj(
    const float* __restrict__ x, const f16* __restrict__ wqB,
    f16* __restrict__ qw, f16* __restrict__ kw, f16* __restrict__ vw, int s)
{
    const int winG = blockIdx.x, idx = blockIdx.y;
    const int b = winG >> 4, wi = winG & 15;
    const int tid = threadIdx.x;
    const int wave = tid >> 6, lane = tid & 63, g = lane >> 4, ln = lane & 15;

    union __align__(16) SM {
        f16 xa[32 * 256 * 4];   // 64 KB  A chunked [kc(32)][t(256)][kj(4)]
        f16 pt[128 * 136];      // 34.8 KB transpose tile [c(128)][t-half pad136]
    };
    __shared__ SM sm;

    // stage x -> f16 chunked LDS (rolled channels/rows)
    {
        int t = tid;
        int h, w;
        if (idx == 0) { h = t >> 2;            w = wi * 4 + (t & 3); }
        else          { h = wi * 4 + (t >> 6); w = t & 63; }
        int gh = (h + s) & 63;
        const float* xrow = x + ((size_t)b << 20) + (gh << 6) + w;
        for (int c = 0; c < 128; ++c) {
            int gc = (idx * 128 + c + s) & 255;
            sm.xa[((c >> 2) * 256 + t) * 4 + (c & 3)] = (f16)xrow[(size_t)gc << 12];
        }
    }
    __syncthreads();

    // A-frags to registers (held across all 3 parts): A[m=t][k=c]
    half4 af[4][8];
    #pragma unroll
    for (int mt = 0; mt < 4; ++mt)
        #pragma unroll
        for (int kt = 0; kt < 8; ++kt) {
            int t = wave * 64 + mt * 16 + ln;
            af[mt][kt] = *(const half4*)&sm.xa[((kt * 4 + g) * 256 + t) * 4];
        }
    __syncthreads();

    for (int part = 0; part < 3; ++part) {
        floatx4 C[8][4];
        #pragma unroll
        for (int nt = 0; nt < 8; ++nt)
            #pragma unroll
            for (int mt = 0; mt < 4; ++mt) C[nt][mt] = (floatx4){0.f, 0.f, 0.f, 0.f};

        for (int kt = 0; kt < 8; ++kt) {
            half4 bf[8];
            #pragma unroll
            for (int nt = 0; nt < 8; ++nt)
                bf[nt] = *(const half4*)&wqB[((((part * 8 + kt) * 8 + nt) * 64) + lane) * 4];
            #pragma unroll
            for (int nt = 0; nt < 8; ++nt)
                #pragma unroll
                for (int mt = 0; mt < 4; ++mt)
                    C[nt][mt] = __builtin_amdgcn_mfma_f32_16x16x16f16(
                        af[mt][kt], bf[nt], C[nt][mt], 0, 0, 0);
        }

        f16* dst = (part == 0 ? qw : (part == 1 ? kw : vw)) + (size_t)idx * WIN;
        const float qsc = (part == 0) ? 0.25f : 1.0f;   // fold softmax scale

        for (int th = 0; th < 2; ++th) {
            __syncthreads();
            if ((wave >> 1) == th) {        // waves owning this t-half
                #pragma unroll
                for (int nt = 0; nt < 8; ++nt)
                    #pragma unroll
                    for (int mt = 0; mt < 4; ++mt)
                        #pragma unroll
                        for (int r = 0; r < 4; ++r) {
                            int tl = wave * 64 + mt * 16 + g * 4 + r - th * 128;
                            sm.pt[(nt * 16 + ln) * 136 + tl] = (f16)(C[nt][mt][r] * qsc);
                        }
            }
            __syncthreads();
            // cooperative coalesced store: [c][t] -> [head][d][t]
            int tg = tid & 15, hcq = tid >> 4;
            #pragma unroll
            for (int it = 0; it < 8; ++it) {
                int hc = it * 16 + hcq;          // head*16 + d
                int d = hc & 15, head = hc >> 4;
                int c = d * 8 + head;            // part-local channel
                float4 v4 = *(const float4*)&sm.pt[c * 136 + tg * 8];
                *(float4*)(dst + ((((size_t)(winG * 8 + head) * 16) + d) << 8)
                               + th * 128 + tg * 8) = v4;
            }
        }
    }
}

// ---- LePE dwconv3x3 from vw (window remap for halo), c-major output
// grid (128 winG, 2 idx, 8 hc-groups), 256 threads = t
__global__ __launch_bounds__(256) void k_lepe(
    const f16* __restrict__ vw, const float* __restrict__ wle,
    const float* __restrict__ ble, f16* __restrict__ lepe)
{
    const int winG = blockIdx.x, idx = blockIdx.y, hcg = blockIdx.z;
    const int b = winG >> 4, wi = winG & 15;
    const int t = threadIdx.x;
    int h0, w0;
    if (idx == 0) { h0 = t >> 2;            w0 = wi * 4 + (t & 3); }
    else          { h0 = wi * 4 + (t >> 6); w0 = t & 63; }
    const f16* vb = vw + (size_t)idx * WIN;
    f16* lb = lepe + (size_t)idx * WIN;

    for (int i = 0; i < 16; ++i) {
        int hc = hcg * 16 + i;
        int d = hc & 15, head = hc >> 4;
        int c = d * 8 + head;
        float acc = ble[c];
        #pragma unroll
        for (int ky = 0; ky < 3; ++ky) {
            int hh = h0 + ky - 1;
            if (hh < 0 || hh > 63) continue;
            #pragma unroll
            for (int kx = 0; kx < 3; ++kx) {
                int ww = w0 + kx - 1;
                if (ww < 0 || ww > 63) continue;
                int wg2, t2;
                if (idx == 0) { wg2 = b * 16 + (ww >> 2); t2 = (hh << 2) | (ww & 3); }
                else          { wg2 = b * 16 + (hh >> 2); t2 = ((hh & 3) << 6) | ww; }
                acc = fmaf(wle[c * 9 + ky * 3 + kx],
                           (float)vb[(((size_t)(wg2 * 8 + head) * 16 + d) << 8) + t2],
                           acc);
            }
        }
        lb[(((size_t)(winG * 8 + head) * 16 + d) << 8) + t] = (f16)acc;
    }
}

// ---- MFMA attention + LePE add, writes ow (c-major f16), no RMW
// 1024 blocks x 256 threads; wave = (winG, idx, head, qhalf)
__global__ __launch_bounds__(256) void k_attn(
    const f16* __restrict__ qw, const f16* __restrict__ kw,
    const f16* __restrict__ vw, const f16* __restrict__ lep,
    f16* __restrict__ ow)
{
    const int lane = threadIdx.x & 63;
    const int g = lane >> 4, ln = lane & 15;
    const int W = blockIdx.x * 4 + (threadIdx.x >> 6);
    const int qhalf = W & 1, head = (W >> 1) & 7, idx = (W >> 4) & 1, winG = W >> 5;

    const size_t cb = ((size_t)(winG * 8 + head)) << 4;   // + d, then <<8 for t
    const f16* qb = qw + (size_t)idx * WIN;
    const f16* kb = kw + (size_t)idx * WIN;
    const f16* vb = vw + (size_t)idx * WIN;
    const f16* lb = lep + (size_t)idx * WIN;
    f16* ob = ow + (size_t)idx * WIN;

    half4 qf[8];
    #pragma unroll
    for (int qt = 0; qt < 8; ++qt) {
        int t = qhalf * 128 + qt * 16 + ln;
        #pragma unroll
        for (int j = 0; j < 4; ++j)
            qf[qt][j] = qb[((cb + g * 4 + j) << 8) + t];
    }

    floatx4 o[8]; float lsum[8];
    #pragma unroll
    for (int qt = 0; qt < 8; ++qt) { o[qt] = (floatx4){0.f,0.f,0.f,0.f}; lsum[qt] = 0.f; }

    for (int kt = 0; kt < 16; ++kt) {
        half4 kf, vf;
        int tk = kt * 16 + ln;
        #pragma unroll
        for (int j = 0; j < 4; ++j)
            kf[j] = kb[((cb + g * 4 + j) << 8) + tk];
        vf = *(const half4*)&vb[((cb + ln) << 8) + kt * 16 + g * 4];
        #pragma unroll
        for (int qt = 0; qt < 8; ++qt) {
            floatx4 sc = __builtin_amdgcn_mfma_f32_16x16x16f16(
                kf, qf[qt], (floatx4){0.f,0.f,0.f,0.f}, 0, 0, 0);
            float p0 = __expf(sc[0]), p1 = __expf(sc[1]);
            float p2 = __expf(sc[2]), p3 = __expf(sc[3]);
            lsum[qt] += (p0 + p1) + (p2 + p3);
            half4 pf = {(f16)p0, (f16)p1, (f16)p2, (f16)p3};
            o[qt] = __builtin_amdgcn_mfma_f32_16x16x16f16(vf, pf, o[qt], 0, 0, 0);
        }
    }

    #pragma unroll
    for (int qt = 0; qt < 8; ++qt) {
        float l = lsum[qt];
        l += __shfl_xor(l, 16);
        l += __shfl_xor(l, 32);
        float inv = 1.f / l;
        int t = qhalf * 128 + qt * 16 + ln;
        #pragma unroll
        for (int r = 0; r < 4; ++r) {
            int d = g * 4 + r;
            float val = fmaf(o[qt][r], inv, (float)lb[((cb + d) << 8) + t]);
            ob[((cb + d) << 8) + t] = (f16)val;
        }
    }
}

// ---- combine shifts + inverse roll, single coalesced out write
__global__ __launch_bounds__(256) void k_final(
    const f16* __restrict__ ow0, const f16* __restrict__ ow2,
    float* __restrict__ out)
{
    #pragma unroll
    for (int it = 0; it < 4; ++it) {
        int e = blockIdx.x * 1024 + it * 256 + threadIdx.x;
        int w = e & 63, oh = (e >> 6) & 63, oc = (e >> 12) & 255, b = e >> 20;
        float acc = 0.f;
        #pragma unroll
        for (int si = 0; si < 2; ++si) {
            int s = si * 2;
            const f16* p = si ? ow2 : ow0;
            int idx = oc >> 7;
            int cl = ((oc & 127) - s) & 127;
            int h = (oh - s) & 63;
            int head = cl & 7, d = cl >> 3;
            int wg, t;
            if (idx == 0) { wg = b * 16 + (w >> 2); t = (h << 2) | (w & 3); }
            else          { wg = b * 16 + (h >> 2); t = ((h & 3) << 6) | w; }
            acc += (float)p[(size_t)idx * WIN + (((size_t)(wg * 8 + head) * 16 + d) << 8) + t];
        }
        out[e] = acc;
    }
}

extern "C" void kernel_launch(void* const* d_in, const int* in_sizes, int n_in,
                              void* d_out, int out_size, void* d_ws, size_t ws_size,
                              hipStream_t stream) {
    const float* x      = (const float*)d_in[0];
    const float* w_qkv  = (const float*)d_in[1];
    const float* w_lepe = (const float*)d_in[2];
    const float* b_lepe = (const float*)d_in[3];
    float* out = (float*)d_out;

    f16* wsf = (f16*)d_ws;
    f16* wqB = wsf;                         // 49152 used, 65536 reserved
    f16* qw  = wsf + 65536;
    f16* kw  = qw + 2 * (size_t)WIN;
    f16* vw  = kw + 2 * (size_t)WIN;
    f16* lep = vw + 2 * (size_t)WIN;
    f16* ow0 = lep + 2 * (size_t)WIN;
    f16* ow2 = qw;                          // alias (see header comment)

    k_prep<<<192, 256, 0, stream>>>(w_qkv, wqB);

    k_proj<<<dim3(128, 2), 256, 0, stream>>>(x, wqB, qw, kw, vw, 0);
    k_lepe<<<dim3(128, 2, 8), 256, 0, stream>>>(vw, w_lepe, b_lepe, lep);
    k_attn<<<1024, 256, 0, stream>>>(qw, kw, vw, lep, ow0);

    k_proj<<<dim3(128, 2), 256, 0, stream>>>(x, wqB, qw, kw, vw, 2);
    k_lepe<<<dim3(128, 2, 8), 256, 0, stream>>>(vw, w_lepe, b_lepe, lep);
    k_attn<<<1024, 256, 0, stream>>>(qw, kw, vw, lep, ow2);

    k_final<<<8192, 256, 0, stream>>>(ow0, ow2, out);
}

// Round 5
// 321.185 us; speedup vs baseline: 2.3052x; 1.1060x over previous
//
#include <hip/hip_runtime.h>
#include <hip/hip_bf16.h>

typedef _Float16 f16;
typedef _Float16 half4 __attribute__((ext_vector_type(4)));
typedef float floatx4 __attribute__((ext_vector_type(4)));

// Problem: B=8, C=256, H=W=64, sd=128, HEADS=8, hd=16, window L=256 tokens.
// idx0 = 64x4 column strips (wi = w>>2, t = h*4+(w&3)),
// idx1 = 4x64 row strips   (wi = h>>2, t = (h&3)*64+w).
// Layouts (f16), per idx:
//   qw,kw: token-major [winG(128)][t(256)][hc(128)]   (hc = head*16+d)
//   vw,lepe,ow: c-major [winG(128)][hc(128)][t(256)]
// WIN = elems per [idx] tensor = 4194304.
#define WIN 4194304

// ws (f16 elems): wqB 65536 | qw 2W | kw 2W | vw 2W | lep 2W | ow0 2W.
// ow2 aliases lep: attn reads lb[x] then writes ob[x] at identical element
// addresses, each element owned by exactly one lane -> race-free.

// ---- weight prep: wqB[part][kt][nt][lane][kj] (B-frag-ordered)
__global__ void k_prep(const float* __restrict__ wq, f16* __restrict__ wqB) {
    int D = blockIdx.x * 256 + threadIdx.x;
    if (D >= 49152) return;
    int kj = D & 3, lane = (D >> 2) & 63, nt = (D >> 8) & 7;
    int kt = (D >> 11) & 7, part = D >> 14;
    int g = lane >> 4, ln = lane & 15;
    int o = part * 128 + nt * 16 + ln;
    int k = kt * 16 + g * 4 + kj;
    wqB[D] = (f16)wq[o * 128 + k];
}

// ---- MFMA projection: per window [256 t x 128 c] x [128 c x 384 o]
// grid (128 winG, 2 idx), 256 threads
__global__ __launch_bounds__(256, 1) void k_proj(
    const float* __restrict__ x, const f16* __restrict__ wqB,
    f16* __restrict__ qw, f16* __restrict__ kw, f16* __restrict__ vw, int s)
{
    const int winG = blockIdx.x, idx = blockIdx.y;
    const int b = winG >> 4, wi = winG & 15;
    const int tid = threadIdx.x;
    const int wave = tid >> 6, lane = tid & 63, g = lane >> 4, ln = lane & 15;

    union __align__(16) SM {
        f16 xa[32 * 256 * 4];   // 64 KB  A chunked [kc(32)][t(256)][kj(4)]
        f16 pt[128 * 136];      // transpose tile (v: [hc][t], q/k: [t][hc])
    };
    __shared__ SM sm;

    // stage x -> f16 chunked LDS, float4 along w (rolled channels/rows)
    for (int ii = tid; ii < 128 * 64; ii += 256) {
        int c = ii >> 6, j = ii & 63;
        int gc = (idx * 128 + c + s) & 255;
        int h, w4, t0;
        if (idx == 0) { h = j;                w4 = wi * 4;        t0 = j * 4; }
        else          { h = wi * 4 + (j >> 4); w4 = (j & 15) * 4;
                        t0 = ((j >> 4) << 6) + w4; }
        int gh = (h + s) & 63;
        float4 v4 = *(const float4*)&x[(((size_t)b * 256 + gc) << 12) + (gh << 6) + w4];
        const float* vp = (const float*)&v4;
        #pragma unroll
        for (int jj = 0; jj < 4; ++jj)
            sm.xa[((c >> 2) * 256 + t0 + jj) * 4 + (c & 3)] = (f16)vp[jj];
    }
    __syncthreads();

    // A-frags (held across parts): A[m=t][k=c]
    half4 af[4][8];
    #pragma unroll
    for (int mt = 0; mt < 4; ++mt)
        #pragma unroll
        for (int kt = 0; kt < 8; ++kt) {
            int t = wave * 64 + mt * 16 + ln;
            af[mt][kt] = *(const half4*)&sm.xa[((kt * 4 + g) * 256 + t) * 4];
        }
    __syncthreads();

    for (int part = 0; part < 3; ++part) {
        floatx4 C[8][4];
        #pragma unroll
        for (int nt = 0; nt < 8; ++nt)
            #pragma unroll
            for (int mt = 0; mt < 4; ++mt) C[nt][mt] = (floatx4){0.f, 0.f, 0.f, 0.f};

        for (int kt = 0; kt < 8; ++kt) {
            half4 bf[8];
            #pragma unroll
            for (int nt = 0; nt < 8; ++nt)
                bf[nt] = *(const half4*)&wqB[((((part * 8 + kt) * 8 + nt) * 64) + lane) * 4];
            #pragma unroll
            for (int nt = 0; nt < 8; ++nt)
                #pragma unroll
                for (int mt = 0; mt < 4; ++mt)
                    C[nt][mt] = __builtin_amdgcn_mfma_f32_16x16x16f16(
                        af[mt][kt], bf[nt], C[nt][mt], 0, 0, 0);
        }

        const float qsc = (part == 0) ? 0.25f : 1.0f;   // fold softmax scale

        for (int th = 0; th < 2; ++th) {
            __syncthreads();
            if ((wave >> 1) == th) {
                #pragma unroll
                for (int nt = 0; nt < 8; ++nt)
                    #pragma unroll
                    for (int mt = 0; mt < 4; ++mt)
                        #pragma unroll
                        for (int r = 0; r < 4; ++r) {
                            int tl = wave * 64 + mt * 16 + g * 4 + r - th * 128;
                            int c = nt * 16 + ln;                 // part-local o
                            int hc = ((c & 7) << 4) + (c >> 3);   // head*16+d
                            f16 hv = (f16)(C[nt][mt][r] * qsc);
                            if (part == 2) sm.pt[hc * 136 + tl] = hv;
                            else           sm.pt[tl * 136 + hc] = hv;
                        }
            }
            __syncthreads();
            if (part == 2) {
                // c-major store: [winG][hc][t]
                int tg = tid & 15, hcq = tid >> 4;
                #pragma unroll
                for (int it = 0; it < 8; ++it) {
                    int hc = it * 16 + hcq;
                    float4 v4 = *(const float4*)&sm.pt[hc * 136 + tg * 8];
                    *(float4*)(vw + (size_t)idx * WIN
                               + (((size_t)winG * 128 + hc) << 8) + th * 128 + tg * 8) = v4;
                }
            } else {
                // token-major store: [winG][t][hc]
                f16* dst = (part == 0 ? qw : kw) + (size_t)idx * WIN;
                int hcg = tid & 15, tq = tid >> 4;
                #pragma unroll
                for (int it = 0; it < 8; ++it) {
                    int tl = it * 16 + tq;
                    float4 v4 = *(const float4*)&sm.pt[tl * 136 + hcg * 8];
                    *(float4*)(dst + (((size_t)winG * 256 + th * 128 + tl) << 7)
                               + hcg * 8) = v4;
                }
            }
        }
    }
}

// ---- LePE dwconv3x3 in window domain, LDS halo staging
// grid (128 winG, 2 idx, 16 hc-slices of 8), 256 threads = t
__global__ __launch_bounds__(256) void k_lepe(
    const f16* __restrict__ vw, const float* __restrict__ wle,
    const float* __restrict__ ble, f16* __restrict__ lepe)
{
    const int winG = blockIdx.x, idx = blockIdx.y, hg = blockIdx.z;
    const int wi = winG & 15;
    const int tid = threadIdx.x;
    const int hc0 = hg * 8;
    const f16* vb = vw + (size_t)idx * WIN;
    f16* lb = lepe + (size_t)idx * WIN;

    __shared__ f16 sp[4096];

    if (idx == 0) {
        // view [hcl(8)][h(64)][wp(8)]: wp=0 left halo, 1..4 center, 5 right halo
        for (int ii = tid; ii < 8 * 256; ii += 256) {
            int hcl = ii >> 8, t = ii & 255;
            f16 v = vb[(((size_t)winG * 128 + hc0 + hcl) << 8) + t];
            sp[(hcl << 9) + ((t >> 2) << 3) + 1 + (t & 3)] = v;
        }
        for (int ii = tid; ii < 8 * 128; ii += 256) {
            int hcl = ii >> 7, j = ii & 127;
            int side = j >> 6, h = j & 63;
            f16 v = (f16)0.f;
            if (side == 0) { if (wi > 0)
                v = vb[(((size_t)(winG - 1) * 128 + hc0 + hcl) << 8) + h * 4 + 3]; }
            else           { if (wi < 15)
                v = vb[(((size_t)(winG + 1) * 128 + hc0 + hcl) << 8) + h * 4]; }
            sp[(hcl << 9) + (h << 3) + (side ? 5 : 0)] = v;
        }
        __syncthreads();
        int h = tid >> 2, wp = 1 + (tid & 3);
        for (int hcl = 0; hcl < 8; ++hcl) {
            int hc = hc0 + hcl, d = hc & 15, head = hc >> 4;
            int c = d * 8 + head;
            float acc = ble[c];
            #pragma unroll
            for (int ky = 0; ky < 3; ++ky) {
                int hh = h + ky - 1;
                if (hh < 0 || hh > 63) continue;
                #pragma unroll
                for (int kx = 0; kx < 3; ++kx)
                    acc = fmaf(wle[c * 9 + ky * 3 + kx],
                               (float)sp[(hcl << 9) + (hh << 3) + wp + kx - 1], acc);
            }
            lb[(((size_t)winG * 128 + hc) << 8) + tid] = (f16)acc;
        }
    } else {
        // view [hcl(8)][hp(6)][68]: hp=0 top halo, 1..4 center, 5 bottom halo
        const int ROW = 68;
        for (int ii = tid; ii < 8 * 256; ii += 256) {
            int hcl = ii >> 8, t = ii & 255;
            f16 v = vb[(((size_t)winG * 128 + hc0 + hcl) << 8) + t];
            sp[hcl * 6 * ROW + (1 + (t >> 6)) * ROW + 1 + (t & 63)] = v;
        }
        for (int ii = tid; ii < 8 * 128; ii += 256) {
            int hcl = ii >> 7, j = ii & 127;
            int side = j >> 6, w = j & 63;
            f16 v = (f16)0.f;
            if (side == 0) { if (wi > 0)
                v = vb[(((size_t)(winG - 1) * 128 + hc0 + hcl) << 8) + 192 + w]; }
            else           { if (wi < 15)
                v = vb[(((size_t)(winG + 1) * 128 + hc0 + hcl) << 8) + w]; }
            sp[hcl * 6 * ROW + (side ? 5 : 0) * ROW + 1 + w] = v;
        }
        for (int ii = tid; ii < 8 * 6 * 2; ii += 256) {
            int hcl = ii / 12, rr = (ii % 12) >> 1, e = ii & 1;
            sp[hcl * 6 * ROW + rr * ROW + (e ? 65 : 0)] = (f16)0.f;
        }
        __syncthreads();
        int hloc = tid >> 6, w = tid & 63;
        for (int hcl = 0; hcl < 8; ++hcl) {
            int hc = hc0 + hcl, d = hc & 15, head = hc >> 4;
            int c = d * 8 + head;
            float acc = ble[c];
            #pragma unroll
            for (int ky = 0; ky < 3; ++ky)
                #pragma unroll
                for (int kx = 0; kx < 3; ++kx)
                    acc = fmaf(wle[c * 9 + ky * 3 + kx],
                               (float)sp[hcl * 6 * ROW + (hloc + ky) * ROW + w + kx],
                               acc);
            lb[(((size_t)winG * 128 + hc) << 8) + tid] = (f16)acc;
        }
    }
}

// ---- MFMA attention + LePE add, writes ow (c-major f16)
// 1024 blocks x 256 threads; wave = (winG, idx, head, qhalf)
__global__ __launch_bounds__(256) void k_attn(
    const f16* __restrict__ qw, const f16* __restrict__ kw,
    const f16* __restrict__ vw, const f16* __restrict__ lep,
    f16* __restrict__ ow)
{
    const int lane = threadIdx.x & 63;
    const int g = lane >> 4, ln = lane & 15;
    const int W = blockIdx.x * 4 + (threadIdx.x >> 6);
    const int qhalf = W & 1, head = (W >> 1) & 7, idx = (W >> 4) & 1, winG = W >> 5;

    const size_t cb = ((size_t)(winG * 8 + head)) << 4;   // c-major: (+d)<<8 + t
    const f16* qb = qw + (size_t)idx * WIN + ((size_t)winG << 15) + head * 16;
    const f16* kb = kw + (size_t)idx * WIN + ((size_t)winG << 15) + head * 16;
    const f16* vb = vw + (size_t)idx * WIN;
    const f16* lb = lep + (size_t)idx * WIN;
    f16* ob = ow + (size_t)idx * WIN;

    // Q^T B-frags: B[k=d=g*4+j][n=query=ln]  (token-major: half4)
    half4 qf[8];
    #pragma unroll
    for (int qt = 0; qt < 8; ++qt) {
        int t = qhalf * 128 + qt * 16 + ln;
        qf[qt] = *(const half4*)(qb + ((size_t)t << 7) + g * 4);
    }

    floatx4 o[8]; float lsum[8];
    #pragma unroll
    for (int qt = 0; qt < 8; ++qt) { o[qt] = (floatx4){0.f,0.f,0.f,0.f}; lsum[qt] = 0.f; }

    for (int kt = 0; kt < 16; ++kt) {
        // K A-frag: A[m=key=ln][k=d]  (token-major: half4)
        half4 kf = *(const half4*)(kb + ((size_t)(kt * 16 + ln) << 7) + g * 4);
        // V^T A-frag: A[m=d=ln][k=key] (c-major: half4)
        half4 vf = *(const half4*)&vb[((cb + ln) << 8) + kt * 16 + g * 4];
        #pragma unroll
        for (int qt = 0; qt < 8; ++qt) {
            floatx4 sc = __builtin_amdgcn_mfma_f32_16x16x16f16(
                kf, qf[qt], (floatx4){0.f,0.f,0.f,0.f}, 0, 0, 0);
            float p0 = __expf(sc[0]), p1 = __expf(sc[1]);
            float p2 = __expf(sc[2]), p3 = __expf(sc[3]);
            lsum[qt] += (p0 + p1) + (p2 + p3);
            half4 pf = {(f16)p0, (f16)p1, (f16)p2, (f16)p3};
            o[qt] = __builtin_amdgcn_mfma_f32_16x16x16f16(vf, pf, o[qt], 0, 0, 0);
        }
    }

    #pragma unroll
    for (int qt = 0; qt < 8; ++qt) {
        float l = lsum[qt];
        l += __shfl_xor(l, 16);
        l += __shfl_xor(l, 32);
        float inv = 1.f / l;
        int t = qhalf * 128 + qt * 16 + ln;
        #pragma unroll
        for (int r = 0; r < 4; ++r) {
            int d = g * 4 + r;
            float val = fmaf(o[qt][r], inv, (float)lb[((cb + d) << 8) + t]);
            ob[((cb + d) << 8) + t] = (f16)val;
        }
    }
}

// ---- combine shifts + inverse roll, single coalesced out write
__global__ __launch_bounds__(256) void k_final(
    const f16* __restrict__ ow0, const f16* __restrict__ ow2,
    float* __restrict__ out)
{
    #pragma unroll
    for (int it = 0; it < 4; ++it) {
        int e = blockIdx.x * 1024 + it * 256 + threadIdx.x;
        int w = e & 63, oh = (e >> 6) & 63, oc = (e >> 12) & 255, b = e >> 20;
        float acc = 0.f;
        #pragma unroll
        for (int si = 0; si < 2; ++si) {
            int s = si * 2;
            const f16* p = si ? ow2 : ow0;
            int idx = oc >> 7;
            int cl = ((oc & 127) - s) & 127;
            int h = (oh - s) & 63;
            int head = cl & 7, d = cl >> 3;
            int wg, t;
            if (idx == 0) { wg = b * 16 + (w >> 2); t = (h << 2) | (w & 3); }
            else          { wg = b * 16 + (h >> 2); t = ((h & 3) << 6) | w; }
            acc += (float)p[(size_t)idx * WIN
                            + (((size_t)(wg * 8 + head) * 16 + d) << 8) + t];
        }
        out[e] = acc;
    }
}

extern "C" void kernel_launch(void* const* d_in, const int* in_sizes, int n_in,
                              void* d_out, int out_size, void* d_ws, size_t ws_size,
                              hipStream_t stream) {
    const float* x      = (const float*)d_in[0];
    const float* w_qkv  = (const float*)d_in[1];
    const float* w_lepe = (const float*)d_in[2];
    const float* b_lepe = (const float*)d_in[3];
    float* out = (float*)d_out;

    f16* wsf = (f16*)d_ws;
    f16* wqB = wsf;                         // 49152 used, 65536 reserved
    f16* qw  = wsf + 65536;
    f16* kw  = qw + 2 * (size_t)WIN;
    f16* vw  = kw + 2 * (size_t)WIN;
    f16* lep = vw + 2 * (size_t)WIN;
    f16* ow0 = lep + 2 * (size_t)WIN;
    f16* ow2 = lep;                         // alias (see header comment)

    k_prep<<<192, 256, 0, stream>>>(w_qkv, wqB);

    k_proj<<<dim3(128, 2), 256, 0, stream>>>(x, wqB, qw, kw, vw, 0);
    k_lepe<<<dim3(128, 2, 16), 256, 0, stream>>>(vw, w_lepe, b_lepe, lep);
    k_attn<<<1024, 256, 0, stream>>>(qw, kw, vw, lep, ow0);

    k_proj<<<dim3(128, 2), 256, 0, stream>>>(x, wqB, qw, kw, vw, 2);
    k_lepe<<<dim3(128, 2, 16), 256, 0, stream>>>(vw, w_lepe, b_lepe, lep);
    k_attn<<<1024, 256, 0, stream>>>(qw, kw, vw, lep, ow2);

    k_final<<<8192, 256, 0, stream>>>(ow0, ow2, out);
}

// Round 6
// 273.784 us; speedup vs baseline: 2.7043x; 1.1731x over previous
//
#include <hip/hip_runtime.h>
#include <hip/hip_bf16.h>

typedef _Float16 f16;
typedef _Float16 half4 __attribute__((ext_vector_type(4)));
typedef float floatx4 __attribute__((ext_vector_type(4)));

// Problem: B=8, C=256, H=W=64, sd=128, HEADS=8, hd=16, window L=256 tokens.
// idx0 = 64x4 column strips (wi = w>>2, t = h*4+(w&3)),
// idx1 = 4x64 row strips   (wi = h>>2, t = (h&3)*64+w).
// Layouts (f16), per idx:
//   qw,kw: token-major [winG(128)][t(256)][hc(128)]   (hc = head*16+d)
//   vw,lepe,ow: c-major [winG(128)][hc(128)][t(256)]
// WIN = elems per [idx] tensor = 4194304.
#define WIN 4194304

// ws (f16 elems): wqB 65536 | qw 2W | kw 2W | vw 2W | lep 2W | ow0 2W.
// ow2 aliases lep: attn reads lb[x] then writes ob[x] at identical element
// addresses, each element owned by exactly one lane -> race-free.

// ---- weight prep: wqB[part][kt][nt][lane][kj] (B-frag-ordered)
__global__ void k_prep(const float* __restrict__ wq, f16* __restrict__ wqB) {
    int D = blockIdx.x * 256 + threadIdx.x;
    if (D >= 49152) return;
    int kj = D & 3, lane = (D >> 2) & 63, nt = (D >> 8) & 7;
    int kt = (D >> 11) & 7, part = D >> 14;
    int g = lane >> 4, ln = lane & 15;
    int o = part * 128 + nt * 16 + ln;
    int k = kt * 16 + g * 4 + kj;
    wqB[D] = (f16)wq[o * 128 + k];
}

// ---- MFMA projection, pixel-row tiled: M=128 px (2 h-rows), K=128, N=384
// grid (32 row-pairs, 8 b, 2 idx) = 512 blocks, 256 threads (4 waves, M=32 each)
__global__ __launch_bounds__(256, 2) void k_proj(
    const float* __restrict__ x, const f16* __restrict__ wqB,
    f16* __restrict__ qw, f16* __restrict__ kw, f16* __restrict__ vw, int s)
{
    const int rt = blockIdx.x, b = blockIdx.y, idx = blockIdx.z;
    const int h0 = rt * 2;
    const int tid = threadIdx.x;
    const int wave = tid >> 6, lane = tid & 63, g = lane >> 4, ln = lane & 15;

    union __align__(16) SM {
        f16 xa[32 * 128 * 4];   // 32 KB  A chunked [kc(32)][m(128)][kj(4)]
        f16 pt[128 * 136];      // 34.8 KB transpose tile
    };
    __shared__ SM sm;

    // stage x -> f16 chunked LDS; full 256B rows of x, each element once
    for (int ii = tid; ii < 4096; ii += 256) {
        int c = ii >> 5, j = ii & 31;
        int row = j >> 4, w4 = (j & 15) << 2;
        int gc = (idx * 128 + c + s) & 255;
        int gh = (h0 + row + s) & 63;
        float4 v4 = *(const float4*)&x[(((size_t)b * 256 + gc) << 12) + (gh << 6) + w4];
        const float* vp = (const float*)&v4;
        int m0 = (row << 6) + w4;
        #pragma unroll
        for (int jj = 0; jj < 4; ++jj)
            sm.xa[((c >> 2) * 128 + m0 + jj) * 4 + (c & 3)] = (f16)vp[jj];
    }
    __syncthreads();

    // A-frags (held across parts): A[m=px][k=c]
    half4 af[2][8];
    #pragma unroll
    for (int mt = 0; mt < 2; ++mt)
        #pragma unroll
        for (int kt = 0; kt < 8; ++kt) {
            int m = wave * 32 + mt * 16 + ln;
            af[mt][kt] = *(const half4*)&sm.xa[((kt * 4 + g) * 128 + m) * 4];
        }

    for (int part = 0; part < 3; ++part) {
        floatx4 C[8][2];
        #pragma unroll
        for (int nt = 0; nt < 8; ++nt)
            #pragma unroll
            for (int mt = 0; mt < 2; ++mt) C[nt][mt] = (floatx4){0.f, 0.f, 0.f, 0.f};

        for (int kt = 0; kt < 8; ++kt) {
            half4 bf[8];
            #pragma unroll
            for (int nt = 0; nt < 8; ++nt)
                bf[nt] = *(const half4*)&wqB[((((part * 8 + kt) * 8 + nt) * 64) + lane) * 4];
            #pragma unroll
            for (int nt = 0; nt < 8; ++nt)
                #pragma unroll
                for (int mt = 0; mt < 2; ++mt)
                    C[nt][mt] = __builtin_amdgcn_mfma_f32_16x16x16f16(
                        af[mt][kt], bf[nt], C[nt][mt], 0, 0, 0);
        }

        const float qsc = (part == 0) ? 0.25f : 1.0f;   // fold softmax scale

        __syncthreads();    // xa (part0) / previous pt reads done
        #pragma unroll
        for (int nt = 0; nt < 8; ++nt)
            #pragma unroll
            for (int mt = 0; mt < 2; ++mt)
                #pragma unroll
                for (int r = 0; r < 4; ++r) {
                    int m = wave * 32 + mt * 16 + g * 4 + r;
                    int c = nt * 16 + ln;                 // part-local o
                    int hc = ((c & 7) << 4) + (c >> 3);   // head*16+d
                    f16 hv = (f16)(C[nt][mt][r] * qsc);
                    if (part == 2) sm.pt[hc * 136 + m] = hv;   // v: [hc][m]
                    else           sm.pt[m * 136 + hc] = hv;   // q/k: [m][hc]
                }
        __syncthreads();

        if (part < 2) {
            // token-major store: [winG][t][hc], 256B-contiguous per m
            f16* dst = (part == 0 ? qw : kw) + (size_t)idx * WIN;
            int tq = tid >> 4, hcg = tid & 15;
            #pragma unroll
            for (int it = 0; it < 8; ++it) {
                int m = it * 16 + tq;
                int h = h0 + (m >> 6), w = m & 63;
                int winG, t;
                if (idx == 0) { winG = b * 16 + (w >> 2); t = (h << 2) | (w & 3); }
                else          { winG = b * 16 + (h >> 2); t = ((h & 3) << 6) | w; }
                *(float4*)(dst + (((size_t)winG * 256 + t) << 7) + hcg * 8) =
                    *(const float4*)&sm.pt[m * 136 + hcg * 8];
            }
        } else {
            // c-major store: [winG][hc][t]
            f16* dst = vw + (size_t)idx * WIN;
            int mg = tid & 15, hcq = tid >> 4;
            int row = mg >> 3, h = h0 + row;
            #pragma unroll
            for (int it = 0; it < 8; ++it) {
                int hc = it * 16 + hcq;
                if (idx == 1) {
                    int w = (mg & 7) * 8;
                    int winG = b * 16 + (h >> 2);
                    int t = ((h & 3) << 6) | w;
                    *(float4*)(dst + (((size_t)winG * 128 + hc) << 8) + t) =
                        *(const float4*)&sm.pt[hc * 136 + mg * 8];
                } else {
                    #pragma unroll
                    for (int q2 = 0; q2 < 2; ++q2) {
                        int w0 = (mg & 7) * 8 + q2 * 4;
                        int winG = b * 16 + (w0 >> 2);
                        int t = h << 2;   // +0..3 via the 4 consecutive elems
                        *(half4*)(dst + (((size_t)winG * 128 + hc) << 8) + t) =
                            *(const half4*)&sm.pt[hc * 136 + mg * 8 + q2 * 4];
                    }
                }
            }
        }
    }
}

// ---- LePE dwconv3x3 in window domain, LDS halo staging
// grid (128 winG, 2 idx, 16 hc-slices of 8), 256 threads = t
__global__ __launch_bounds__(256) void k_lepe(
    const f16* __restrict__ vw, const float* __restrict__ wle,
    const float* __restrict__ ble, f16* __restrict__ lepe)
{
    const int winG = blockIdx.x, idx = blockIdx.y, hg = blockIdx.z;
    const int wi = winG & 15;
    const int tid = threadIdx.x;
    const int hc0 = hg * 8;
    const f16* vb = vw + (size_t)idx * WIN;
    f16* lb = lepe + (size_t)idx * WIN;

    __shared__ f16 sp[4096];

    if (idx == 0) {
        // view [hcl(8)][h(64)][wp(8)]: wp=0 left halo, 1..4 center, 5 right halo
        for (int ii = tid; ii < 8 * 256; ii += 256) {
            int hcl = ii >> 8, t = ii & 255;
            f16 v = vb[(((size_t)winG * 128 + hc0 + hcl) << 8) + t];
            sp[(hcl << 9) + ((t >> 2) << 3) + 1 + (t & 3)] = v;
        }
        for (int ii = tid; ii < 8 * 128; ii += 256) {
            int hcl = ii >> 7, j = ii & 127;
            int side = j >> 6, h = j & 63;
            f16 v = (f16)0.f;
            if (side == 0) { if (wi > 0)
                v = vb[(((size_t)(winG - 1) * 128 + hc0 + hcl) << 8) + h * 4 + 3]; }
            else           { if (wi < 15)
                v = vb[(((size_t)(winG + 1) * 128 + hc0 + hcl) << 8) + h * 4]; }
            sp[(hcl << 9) + (h << 3) + (side ? 5 : 0)] = v;
        }
        __syncthreads();
        int h = tid >> 2, wp = 1 + (tid & 3);
        for (int hcl = 0; hcl < 8; ++hcl) {
            int hc = hc0 + hcl, d = hc & 15, head = hc >> 4;
            int c = d * 8 + head;
            float acc = ble[c];
            #pragma unroll
            for (int ky = 0; ky < 3; ++ky) {
                int hh = h + ky - 1;
                if (hh < 0 || hh > 63) continue;
                #pragma unroll
                for (int kx = 0; kx < 3; ++kx)
                    acc = fmaf(wle[c * 9 + ky * 3 + kx],
                               (float)sp[(hcl << 9) + (hh << 3) + wp + kx - 1], acc);
            }
            lb[(((size_t)winG * 128 + hc) << 8) + tid] = (f16)acc;
        }
    } else {
        // view [hcl(8)][hp(6)][68]: hp=0 top halo, 1..4 center, 5 bottom halo
        const int ROW = 68;
        for (int ii = tid; ii < 8 * 256; ii += 256) {
            int hcl = ii >> 8, t = ii & 255;
            f16 v = vb[(((size_t)winG * 128 + hc0 + hcl) << 8) + t];
            sp[hcl * 6 * ROW + (1 + (t >> 6)) * ROW + 1 + (t & 63)] = v;
        }
        for (int ii = tid; ii < 8 * 128; ii += 256) {
            int hcl = ii >> 7, j = ii & 127;
            int side = j >> 6, w = j & 63;
            f16 v = (f16)0.f;
            if (side == 0) { if (wi > 0)
                v = vb[(((size_t)(winG - 1) * 128 + hc0 + hcl) << 8) + 192 + w]; }
            else           { if (wi < 15)
                v = vb[(((size_t)(winG + 1) * 128 + hc0 + hcl) << 8) + w]; }
            sp[hcl * 6 * ROW + (side ? 5 : 0) * ROW + 1 + w] = v;
        }
        for (int ii = tid; ii < 8 * 6 * 2; ii += 256) {
            int hcl = ii / 12, rr = (ii % 12) >> 1, e = ii & 1;
            sp[hcl * 6 * ROW + rr * ROW + (e ? 65 : 0)] = (f16)0.f;
        }
        __syncthreads();
        int hloc = tid >> 6, w = tid & 63;
        for (int hcl = 0; hcl < 8; ++hcl) {
            int hc = hc0 + hcl, d = hc & 15, head = hc >> 4;
            int c = d * 8 + head;
            float acc = ble[c];
            #pragma unroll
            for (int ky = 0; ky < 3; ++ky)
                #pragma unroll
                for (int kx = 0; kx < 3; ++kx)
                    acc = fmaf(wle[c * 9 + ky * 3 + kx],
                               (float)sp[hcl * 6 * ROW + (hloc + ky) * ROW + w + kx],
                               acc);
            lb[(((size_t)winG * 128 + hc) << 8) + tid] = (f16)acc;
        }
    }
}

// ---- MFMA attention + LePE add, writes ow (c-major f16)
// 1024 blocks x 256 threads; wave = (winG, idx, head, qhalf)
__global__ __launch_bounds__(256) void k_attn(
    const f16* __restrict__ qw, const f16* __restrict__ kw,
    const f16* __restrict__ vw, const f16* __restrict__ lep,
    f16* __restrict__ ow)
{
    const int lane = threadIdx.x & 63;
    const int g = lane >> 4, ln = lane & 15;
    const int W = blockIdx.x * 4 + (threadIdx.x >> 6);
    const int qhalf = W & 1, head = (W >> 1) & 7, idx = (W >> 4) & 1, winG = W >> 5;

    const size_t cb = ((size_t)(winG * 8 + head)) << 4;   // c-major: (+d)<<8 + t
    const f16* qb = qw + (size_t)idx * WIN + ((size_t)winG << 15) + head * 16;
    const f16* kb = kw + (size_t)idx * WIN + ((size_t)winG << 15) + head * 16;
    const f16* vb = vw + (size_t)idx * WIN;
    const f16* lb = lep + (size_t)idx * WIN;
    f16* ob = ow + (size_t)idx * WIN;

    // Q^T B-frags: B[k=d=g*4+j][n=query=ln]  (token-major: half4)
    half4 qf[8];
    #pragma unroll
    for (int qt = 0; qt < 8; ++qt) {
        int t = qhalf * 128 + qt * 16 + ln;
        qf[qt] = *(const half4*)(qb + ((size_t)t << 7) + g * 4);
    }

    floatx4 o[8]; float lsum[8];
    #pragma unroll
    for (int qt = 0; qt < 8; ++qt) { o[qt] = (floatx4){0.f,0.f,0.f,0.f}; lsum[qt] = 0.f; }

    for (int kt = 0; kt < 16; ++kt) {
        // K A-frag: A[m=key=ln][k=d]  (token-major: half4)
        half4 kf = *(const half4*)(kb + ((size_t)(kt * 16 + ln) << 7) + g * 4);
        // V^T A-frag: A[m=d=ln][k=key] (c-major: half4)
        half4 vf = *(const half4*)&vb[((cb + ln) << 8) + kt * 16 + g * 4];
        #pragma unroll
        for (int qt = 0; qt < 8; ++qt) {
            floatx4 sc = __builtin_amdgcn_mfma_f32_16x16x16f16(
                kf, qf[qt], (floatx4){0.f,0.f,0.f,0.f}, 0, 0, 0);
            float p0 = __expf(sc[0]), p1 = __expf(sc[1]);
            float p2 = __expf(sc[2]), p3 = __expf(sc[3]);
            lsum[qt] += (p0 + p1) + (p2 + p3);
            half4 pf = {(f16)p0, (f16)p1, (f16)p2, (f16)p3};
            o[qt] = __builtin_amdgcn_mfma_f32_16x16x16f16(vf, pf, o[qt], 0, 0, 0);
        }
    }

    #pragma unroll
    for (int qt = 0; qt < 8; ++qt) {
        float l = lsum[qt];
        l += __shfl_xor(l, 16);
        l += __shfl_xor(l, 32);
        float inv = 1.f / l;
        int t = qhalf * 128 + qt * 16 + ln;
        #pragma unroll
        for (int r = 0; r < 4; ++r) {
            int d = g * 4 + r;
            float val = fmaf(o[qt][r], inv, (float)lb[((cb + d) << 8) + t]);
            ob[((cb + d) << 8) + t] = (f16)val;
        }
    }
}

// ---- combine shifts + inverse roll, single coalesced out write
__global__ __launch_bounds__(256) void k_final(
    const f16* __restrict__ ow0, const f16* __restrict__ ow2,
    float* __restrict__ out)
{
    #pragma unroll
    for (int it = 0; it < 4; ++it) {
        int e = blockIdx.x * 1024 + it * 256 + threadIdx.x;
        int w = e & 63, oh = (e >> 6) & 63, oc = (e >> 12) & 255, b = e >> 20;
        float acc = 0.f;
        #pragma unroll
        for (int si = 0; si < 2; ++si) {
            int s = si * 2;
            const f16* p = si ? ow2 : ow0;
            int idx = oc >> 7;
            int cl = ((oc & 127) - s) & 127;
            int h = (oh - s) & 63;
            int head = cl & 7, d = cl >> 3;
            int wg, t;
            if (idx == 0) { wg = b * 16 + (w >> 2); t = (h << 2) | (w & 3); }
            else          { wg = b * 16 + (h >> 2); t = ((h & 3) << 6) | w; }
            acc += (float)p[(size_t)idx * WIN
                            + (((size_t)(wg * 8 + head) * 16 + d) << 8) + t];
        }
        out[e] = acc;
    }
}

extern "C" void kernel_launch(void* const* d_in, const int* in_sizes, int n_in,
                              void* d_out, int out_size, void* d_ws, size_t ws_size,
                              hipStream_t stream) {
    const float* x      = (const float*)d_in[0];
    const float* w_qkv  = (const float*)d_in[1];
    const float* w_lepe = (const float*)d_in[2];
    const float* b_lepe = (const float*)d_in[3];
    float* out = (float*)d_out;

    f16* wsf = (f16*)d_ws;
    f16* wqB = wsf;                         // 49152 used, 65536 reserved
    f16* qw  = wsf + 65536;
    f16* kw  = qw + 2 * (size_t)WIN;
    f16* vw  = kw + 2 * (size_t)WIN;
    f16* lep = vw + 2 * (size_t)WIN;
    f16* ow0 = lep + 2 * (size_t)WIN;
    f16* ow2 = lep;                         // alias (see header comment)

    k_prep<<<192, 256, 0, stream>>>(w_qkv, wqB);

    k_proj<<<dim3(32, 8, 2), 256, 0, stream>>>(x, wqB, qw, kw, vw, 0);
    k_lepe<<<dim3(128, 2, 16), 256, 0, stream>>>(vw, w_lepe, b_lepe, lep);
    k_attn<<<1024, 256, 0, stream>>>(qw, kw, vw, lep, ow0);

    k_proj<<<dim3(32, 8, 2), 256, 0, stream>>>(x, wqB, qw, kw, vw, 2);
    k_lepe<<<dim3(128, 2, 16), 256, 0, stream>>>(vw, w_lepe, b_lepe, lep);
    k_attn<<<1024, 256, 0, stream>>>(qw, kw, vw, lep, ow2);

    k_final<<<8192, 256, 0, stream>>>(ow0, ow2, out);
}